// Round 1
// baseline (455.415 us; speedup 1.0000x reference)
//
#include <hip/hip_runtime.h>
#include <hip/hip_bf16.h>

#define CDIV(a,b) (((a)+(b)-1)/(b))

// ---------------------------------------------------------------------------
// Edge-buffer layout detection: if the harness kept int64 (little-endian),
// every odd 32-bit word (high half of a value < 50000) is 0. If it converted
// to int32, odd words are edge indices (random in [0,50000)) — some nonzero.
// flag: 0 = int64 layout, 1 = int32 layout.  Benign write race (all write 1).
// ---------------------------------------------------------------------------
__global__ void detect_kernel(const int* __restrict__ edges, int* __restrict__ flag, int E) {
    int i = blockIdx.x * blockDim.x + threadIdx.x;
    if (i < E) {
        if (edges[2 * i + 1] != 0) *flag = 1;
    }
}

__device__ __forceinline__ int load_src(const int* e, int f, int E, int i) {
    return f ? e[i] : e[2 * i];
}
__device__ __forceinline__ int load_dst(const int* e, int f, int E, int i) {
    return f ? e[E + i] : e[2 * (E + i)];
}

__global__ void count_kernel(const int* __restrict__ edges, const int* __restrict__ flag,
                             int* __restrict__ counts, int E) {
    int e = blockIdx.x * blockDim.x + threadIdx.x;
    if (e >= E) return;
    int f = *flag;
    int d = load_dst(edges, f, E, e);
    atomicAdd(&counts[d], 1);
}

__global__ void dis_kernel(const int* __restrict__ counts, float* __restrict__ dis, int N) {
    int i = blockIdx.x * blockDim.x + threadIdx.x;
    if (i < N) dis[i] = rsqrtf((float)(counts[i] + 1));   // +1 = self-loop
}

// Single-block exclusive scan (N+1 entries of row_ptr). 1024 threads, shfl scans.
__global__ void scan_kernel(const int* __restrict__ counts, int* __restrict__ row_ptr, int N) {
    __shared__ int wsum[16];
    __shared__ int carry_s;
    int tid = threadIdx.x;
    int lane = tid & 63, wv = tid >> 6;
    if (tid == 0) carry_s = 0;
    __syncthreads();
    for (int base = 0; base < N + 1; base += 1024) {
        int i = base + tid;
        int v = (i < N) ? counts[i] : 0;
        int x = v;
        #pragma unroll
        for (int off = 1; off < 64; off <<= 1) {
            int t = __shfl_up(x, off, 64);
            if (lane >= off) x += t;
        }
        if (lane == 63) wsum[wv] = x;
        __syncthreads();
        if (wv == 0 && lane < 16) {
            int y = wsum[lane];
            #pragma unroll
            for (int off = 1; off < 16; off <<= 1) {
                int t = __shfl_up(y, off, 64);
                if (lane >= off) y += t;
            }
            wsum[lane] = y;
        }
        __syncthreads();
        int waveoff = (wv == 0) ? 0 : wsum[wv - 1];
        int carry = carry_s;
        if (i <= N) row_ptr[i] = carry + waveoff + x - v;   // exclusive prefix
        __syncthreads();
        if (tid == 0) carry_s = carry + wsum[15];
        __syncthreads();
    }
}

__global__ void fill_kernel(const int* __restrict__ edges, const int* __restrict__ flag,
                            const int* __restrict__ row_ptr, int* __restrict__ fillc,
                            int* __restrict__ col, int E) {
    int e = blockIdx.x * blockDim.x + threadIdx.x;
    if (e >= E) return;
    int f = *flag;
    int s = load_src(edges, f, E, e);
    int d = load_dst(edges, f, E, e);
    int pos = row_ptr[d] + atomicAdd(&fillc[d], 1);
    col[pos] = s;
}

// ---------------------------------------------------------------------------
// fp32 GEMM: out[N,128] = X[N,128] @ W[128,128].  64-row tile, BK=32.
// Each thread: 4 rows x 8 cols.  W-tile padded (+4) to dodge bank conflicts.
// ---------------------------------------------------------------------------
__global__ __launch_bounds__(256) void gemm_kernel(const float* __restrict__ X,
                                                   const float* __restrict__ W,
                                                   float* __restrict__ out, int N) {
    __shared__ float Xs[64][32];      // 8 KB
    __shared__ float Ws[32][132];     // ~16.9 KB (padded)
    int tid = threadIdx.x;
    int tx = tid & 15;                // 16 col-groups of 8
    int ty = tid >> 4;                // 16 row-groups of 4
    int row0 = blockIdx.x * 64;
    float acc[4][8];
    #pragma unroll
    for (int i = 0; i < 4; ++i)
        #pragma unroll
        for (int j = 0; j < 8; ++j) acc[i][j] = 0.f;

    for (int kt = 0; kt < 128; kt += 32) {
        #pragma unroll
        for (int it = 0; it < 2; ++it) {          // X tile: 512 float4
            int f = tid + it * 256;
            int r = f >> 3;
            int c4 = f & 7;
            float4 v = make_float4(0.f, 0.f, 0.f, 0.f);
            int gr = row0 + r;
            if (gr < N) v = *(const float4*)(X + (size_t)gr * 128 + kt + c4 * 4);
            *(float4*)(&Xs[r][c4 * 4]) = v;
        }
        #pragma unroll
        for (int it = 0; it < 4; ++it) {          // W tile: 1024 float4
            int f = tid + it * 256;
            int r = f >> 5;
            int c4 = f & 31;
            float4 v = *(const float4*)(W + (size_t)(kt + r) * 128 + c4 * 4);
            *(float4*)(&Ws[r][c4 * 4]) = v;
        }
        __syncthreads();
        #pragma unroll
        for (int k4 = 0; k4 < 32; k4 += 4) {
            float4 xv[4];
            #pragma unroll
            for (int i = 0; i < 4; ++i)
                xv[i] = *(const float4*)(&Xs[ty * 4 + i][k4]);
            #pragma unroll
            for (int q = 0; q < 4; ++q) {
                float4 wa = *(const float4*)(&Ws[k4 + q][tx * 8]);
                float4 wb = *(const float4*)(&Ws[k4 + q][tx * 8 + 4]);
                #pragma unroll
                for (int i = 0; i < 4; ++i) {
                    float xs = (q == 0) ? xv[i].x : (q == 1) ? xv[i].y
                             : (q == 2) ? xv[i].z : xv[i].w;
                    acc[i][0] += xs * wa.x; acc[i][1] += xs * wa.y;
                    acc[i][2] += xs * wa.z; acc[i][3] += xs * wa.w;
                    acc[i][4] += xs * wb.x; acc[i][5] += xs * wb.y;
                    acc[i][6] += xs * wb.z; acc[i][7] += xs * wb.w;
                }
            }
        }
        __syncthreads();
    }
    #pragma unroll
    for (int i = 0; i < 4; ++i) {
        int gr = row0 + ty * 4 + i;
        if (gr < N) {
            float4 o0 = make_float4(acc[i][0], acc[i][1], acc[i][2], acc[i][3]);
            float4 o1 = make_float4(acc[i][4], acc[i][5], acc[i][6], acc[i][7]);
            *(float4*)(out + (size_t)gr * 128 + tx * 8) = o0;
            *(float4*)(out + (size_t)gr * 128 + tx * 8 + 4) = o1;
        }
    }
}

// ---------------------------------------------------------------------------
// Aggregation: one 64-lane wave per destination node; float2 per lane (128 f).
// acc starts with the analytic self-loop  h[i] * dis[i]^2, then CSR gathers.
// Epilogue: + bias, relu.
// ---------------------------------------------------------------------------
__global__ __launch_bounds__(256) void agg_kernel(const float* __restrict__ H,
                                                  const int* __restrict__ row_ptr,
                                                  const int* __restrict__ col,
                                                  const float* __restrict__ dis,
                                                  const float* __restrict__ bias,
                                                  float* __restrict__ out, int N) {
    int wid = (blockIdx.x * blockDim.x + threadIdx.x) >> 6;
    int lane = threadIdx.x & 63;
    if (wid >= N) return;
    const float2* H2 = (const float2*)H;
    float dd = dis[wid];
    float2 h = H2[(size_t)wid * 64 + lane];
    float wself = dd * dd;
    float2 acc = make_float2(h.x * wself, h.y * wself);
    int e0 = row_ptr[wid], e1 = row_ptr[wid + 1];
    for (int e = e0; e < e1; ++e) {
        int s = col[e];
        float w = dis[s] * dd;
        float2 hs = H2[(size_t)s * 64 + lane];
        acc.x += hs.x * w;
        acc.y += hs.y * w;
    }
    float2 b = ((const float2*)bias)[lane];
    float2 o = make_float2(fmaxf(acc.x + b.x, 0.f), fmaxf(acc.y + b.y, 0.f));
    ((float2*)out)[(size_t)wid * 64 + lane] = o;
}

extern "C" void kernel_launch(void* const* d_in, const int* in_sizes, int n_in,
                              void* d_out, int out_size, void* d_ws, size_t ws_size,
                              hipStream_t stream) {
    const float* x    = (const float*)d_in[0];
    const int*  edges = (const int*)d_in[1];
    const float* W1   = (const float*)d_in[2];
    const float* b1   = (const float*)d_in[3];
    const float* W2   = (const float*)d_in[4];
    const float* b2   = (const float*)d_in[5];
    float* out = (float*)d_out;

    const int F = 128;
    const int N = in_sizes[0] / F;
    const int E = in_sizes[1] / 2;

    // workspace layout
    float* A      = (float*)d_ws;              // N*128   GEMM output
    float* B      = A + (size_t)N * F;         // N*128   layer-1 output
    float* dis    = B + (size_t)N * F;         // N
    int*  counts  = (int*)(dis + N);           // N
    int*  row_ptr = counts + N;                // N+1
    int*  fillc   = row_ptr + N + 1;           // N
    int*  col     = fillc + N;                 // E
    int*  flag    = col + E;                   // 1

    // zero counts .. flag (contiguous): N + (N+1) + N + E + 1 ints
    size_t zero_ints = (size_t)(3 * N + 2 + E);
    hipMemsetAsync(counts, 0, zero_ints * sizeof(int), stream);

    detect_kernel<<<CDIV(E, 256), 256, 0, stream>>>(edges, flag, E);
    count_kernel<<<CDIV(E, 256), 256, 0, stream>>>(edges, flag, counts, E);
    dis_kernel<<<CDIV(N, 256), 256, 0, stream>>>(counts, dis, N);
    scan_kernel<<<1, 1024, 0, stream>>>(counts, row_ptr, N);
    fill_kernel<<<CDIV(E, 256), 256, 0, stream>>>(edges, flag, row_ptr, fillc, col, E);

    // layer 1
    gemm_kernel<<<CDIV(N, 64), 256, 0, stream>>>(x, W1, A, N);
    agg_kernel<<<CDIV(N * 64, 256), 256, 0, stream>>>(A, row_ptr, col, dis, b1, B, N);
    // layer 2
    gemm_kernel<<<CDIV(N, 64), 256, 0, stream>>>(B, W2, A, N);
    agg_kernel<<<CDIV(N * 64, 256), 256, 0, stream>>>(A, row_ptr, col, dis, b2, out, N);
}

// Round 2
// 346.047 us; speedup vs baseline: 1.3161x; 1.3161x over previous
//
#include <hip/hip_runtime.h>
#include <hip/hip_bf16.h>

#define CDIV(a,b) (((a)+(b)-1)/(b))

// ---------------------------------------------------------------------------
// Edge-buffer layout detection: int64 little-endian => odd 32-bit words all 0.
// flag: 0 = int64 layout, 1 = int32 layout. Benign race (all write 1).
// ---------------------------------------------------------------------------
__global__ void detect_kernel(const int* __restrict__ edges, int* __restrict__ flag, int E) {
    int i = blockIdx.x * blockDim.x + threadIdx.x;
    if (i < E) {
        if (edges[2 * i + 1] != 0) *flag = 1;
    }
}

__device__ __forceinline__ int load_src(const int* e, int f, int E, int i) {
    return f ? e[i] : e[2 * i];
}
__device__ __forceinline__ int load_dst(const int* e, int f, int E, int i) {
    return f ? e[E + i] : e[2 * (E + i)];
}

__global__ void count_kernel(const int* __restrict__ edges, const int* __restrict__ flag,
                             int* __restrict__ counts, int E) {
    int e = blockIdx.x * blockDim.x + threadIdx.x;
    if (e >= E) return;
    int f = *flag;
    int d = load_dst(edges, f, E, e);
    atomicAdd(&counts[d], 1);
}

__global__ void dis_kernel(const int* __restrict__ counts, float* __restrict__ dis, int N) {
    int i = blockIdx.x * blockDim.x + threadIdx.x;
    if (i < N) dis[i] = rsqrtf((float)(counts[i] + 1));   // +1 = self-loop
}

// ---------------------------------------------------------------------------
// Multi-block exclusive scan of counts[0..N) -> row_ptr[0..N), row_ptr[N]=E.
// 1024 elements per block (256 thr x 4).
// ---------------------------------------------------------------------------
__global__ __launch_bounds__(256) void scan1_kernel(const int* __restrict__ counts,
                                                    int* __restrict__ bsum, int N) {
    __shared__ int red[4];
    int tid = threadIdx.x;
    int base = blockIdx.x * 1024;
    int s = 0;
    #pragma unroll
    for (int j = 0; j < 4; ++j) {
        int idx = base + tid + j * 256;
        if (idx < N) s += counts[idx];
    }
    #pragma unroll
    for (int off = 32; off >= 1; off >>= 1) s += __shfl_down(s, off, 64);
    if ((tid & 63) == 0) red[tid >> 6] = s;
    __syncthreads();
    if (tid == 0) bsum[blockIdx.x] = red[0] + red[1] + red[2] + red[3];
}

// single wave scans B block-sums (loops if B > 64); also writes row_ptr[N]=E
__global__ void scan2_kernel(const int* __restrict__ bsum, int* __restrict__ boff,
                             int B, int* __restrict__ row_ptr, int N, int E) {
    int lane = threadIdx.x;
    int carry = 0;
    for (int base = 0; base < B; base += 64) {
        int i = base + lane;
        int v = (i < B) ? bsum[i] : 0;
        int x = v;
        #pragma unroll
        for (int off = 1; off < 64; off <<= 1) {
            int t = __shfl_up(x, off, 64);
            if (lane >= off) x += t;
        }
        if (i < B) boff[i] = carry + x - v;
        carry += __shfl(x, 63, 64);
    }
    if (lane == 0) row_ptr[N] = E;
}

__global__ __launch_bounds__(256) void scan3_kernel(const int* __restrict__ counts,
                                                    const int* __restrict__ boff,
                                                    int* __restrict__ row_ptr, int N) {
    __shared__ int wsum[4];
    int tid = threadIdx.x;
    int lane = tid & 63, wv = tid >> 6;
    int base = blockIdx.x * 1024 + tid * 4;
    int c[4];
    #pragma unroll
    for (int j = 0; j < 4; ++j) c[j] = (base + j < N) ? counts[base + j] : 0;
    int tsum = c[0] + c[1] + c[2] + c[3];
    int x = tsum;
    #pragma unroll
    for (int off = 1; off < 64; off <<= 1) {
        int t = __shfl_up(x, off, 64);
        if (lane >= off) x += t;
    }
    int texcl = x - tsum;
    if (lane == 63) wsum[wv] = x;
    __syncthreads();
    int woff = 0;
    for (int w = 0; w < wv; ++w) woff += wsum[w];
    int off0 = boff[blockIdx.x] + woff + texcl;
    int run = 0;
    #pragma unroll
    for (int j = 0; j < 4; ++j) {
        if (base + j < N) row_ptr[base + j] = off0 + run;
        run += c[j];
    }
}

// CSR fill; pre-packs (src, dis[src]) per edge so agg has a 2-deep chain only.
__global__ void fill_kernel(const int* __restrict__ edges, const int* __restrict__ flag,
                            const int* __restrict__ row_ptr, int* __restrict__ fillc,
                            const float* __restrict__ dis, int2* __restrict__ edata, int E) {
    int e = blockIdx.x * blockDim.x + threadIdx.x;
    if (e >= E) return;
    int f = *flag;
    int s = load_src(edges, f, E, e);
    int d = load_dst(edges, f, E, e);
    int pos = row_ptr[d] + atomicAdd(&fillc[d], 1);
    edata[pos] = make_int2(s, __float_as_int(dis[s]));
}

// ---------------------------------------------------------------------------
// fp32 GEMM: out[N,128] = X[N,128] @ W[128,128]. 64-row tile, BK=32.
// ---------------------------------------------------------------------------
__global__ __launch_bounds__(256) void gemm_kernel(const float* __restrict__ X,
                                                   const float* __restrict__ W,
                                                   float* __restrict__ out, int N) {
    __shared__ float Xs[64][32];
    __shared__ float Ws[32][132];
    int tid = threadIdx.x;
    int tx = tid & 15;
    int ty = tid >> 4;
    int row0 = blockIdx.x * 64;
    float acc[4][8];
    #pragma unroll
    for (int i = 0; i < 4; ++i)
        #pragma unroll
        for (int j = 0; j < 8; ++j) acc[i][j] = 0.f;

    for (int kt = 0; kt < 128; kt += 32) {
        #pragma unroll
        for (int it = 0; it < 2; ++it) {
            int f = tid + it * 256;
            int r = f >> 3;
            int c4 = f & 7;
            float4 v = make_float4(0.f, 0.f, 0.f, 0.f);
            int gr = row0 + r;
            if (gr < N) v = *(const float4*)(X + (size_t)gr * 128 + kt + c4 * 4);
            *(float4*)(&Xs[r][c4 * 4]) = v;
        }
        #pragma unroll
        for (int it = 0; it < 4; ++it) {
            int f = tid + it * 256;
            int r = f >> 5;
            int c4 = f & 31;
            float4 v = *(const float4*)(W + (size_t)(kt + r) * 128 + c4 * 4);
            *(float4*)(&Ws[r][c4 * 4]) = v;
        }
        __syncthreads();
        #pragma unroll
        for (int k4 = 0; k4 < 32; k4 += 4) {
            float4 xv[4];
            #pragma unroll
            for (int i = 0; i < 4; ++i)
                xv[i] = *(const float4*)(&Xs[ty * 4 + i][k4]);
            #pragma unroll
            for (int q = 0; q < 4; ++q) {
                float4 wa = *(const float4*)(&Ws[k4 + q][tx * 8]);
                float4 wb = *(const float4*)(&Ws[k4 + q][tx * 8 + 4]);
                #pragma unroll
                for (int i = 0; i < 4; ++i) {
                    float xs = (q == 0) ? xv[i].x : (q == 1) ? xv[i].y
                             : (q == 2) ? xv[i].z : xv[i].w;
                    acc[i][0] += xs * wa.x; acc[i][1] += xs * wa.y;
                    acc[i][2] += xs * wa.z; acc[i][3] += xs * wa.w;
                    acc[i][4] += xs * wb.x; acc[i][5] += xs * wb.y;
                    acc[i][6] += xs * wb.z; acc[i][7] += xs * wb.w;
                }
            }
        }
        __syncthreads();
    }
    #pragma unroll
    for (int i = 0; i < 4; ++i) {
        int gr = row0 + ty * 4 + i;
        if (gr < N) {
            float4 o0 = make_float4(acc[i][0], acc[i][1], acc[i][2], acc[i][3]);
            float4 o1 = make_float4(acc[i][4], acc[i][5], acc[i][6], acc[i][7]);
            *(float4*)(out + (size_t)gr * 128 + tx * 8) = o0;
            *(float4*)(out + (size_t)gr * 128 + tx * 8 + 4) = o1;
        }
    }
}

// ---------------------------------------------------------------------------
// Aggregation: one wave per node, float2/lane. Edge loop unrolled x8 with
// masked batches: invalid slots alias edata[e] (same cacheline, weight 0)
// so MLP stays 8 gathers deep even in the tail, with no extra HBM traffic.
// ---------------------------------------------------------------------------
__global__ __launch_bounds__(256) void agg_kernel(const float* __restrict__ H,
                                                  const int* __restrict__ row_ptr,
                                                  const int2* __restrict__ edata,
                                                  const float* __restrict__ dis,
                                                  const float* __restrict__ bias,
                                                  float* __restrict__ out, int N) {
    int wid = (blockIdx.x * blockDim.x + threadIdx.x) >> 6;
    int lane = threadIdx.x & 63;
    if (wid >= N) return;
    const float2* H2 = (const float2*)H;
    float dd = dis[wid];
    float2 h = H2[(size_t)wid * 64 + lane];
    float wself = dd * dd;
    float2 acc = make_float2(h.x * wself, h.y * wself);
    int e0 = __builtin_amdgcn_readfirstlane(row_ptr[wid]);
    int e1 = __builtin_amdgcn_readfirstlane(row_ptr[wid + 1]);
    for (int e = e0; e < e1; e += 8) {
        int rem = e1 - e;
        int   sj[8];
        float wj[8];
        #pragma unroll
        for (int j = 0; j < 8; ++j) {
            bool valid = j < rem;
            int2 ed = edata[valid ? e + j : e];
            sj[j] = ed.x;
            wj[j] = valid ? __int_as_float(ed.y) * dd : 0.f;
        }
        float2 aj[8];
        #pragma unroll
        for (int j = 0; j < 8; ++j)
            aj[j] = H2[(size_t)sj[j] * 64 + lane];
        #pragma unroll
        for (int j = 0; j < 8; ++j) {
            acc.x += aj[j].x * wj[j];
            acc.y += aj[j].y * wj[j];
        }
    }
    float2 b = ((const float2*)bias)[lane];
    float2 o = make_float2(fmaxf(acc.x + b.x, 0.f), fmaxf(acc.y + b.y, 0.f));
    ((float2*)out)[(size_t)wid * 64 + lane] = o;
}

extern "C" void kernel_launch(void* const* d_in, const int* in_sizes, int n_in,
                              void* d_out, int out_size, void* d_ws, size_t ws_size,
                              hipStream_t stream) {
    const float* x    = (const float*)d_in[0];
    const int*  edges = (const int*)d_in[1];
    const float* W1   = (const float*)d_in[2];
    const float* b1   = (const float*)d_in[3];
    const float* W2   = (const float*)d_in[4];
    const float* b2   = (const float*)d_in[5];
    float* out = (float*)d_out;

    const int F = 128;
    const int N = in_sizes[0] / F;
    const int E = in_sizes[1] / 2;
    const int NB = CDIV(N, 1024);          // scan blocks

    // workspace layout (ints; offsets kept even so int2 edata is 8B-aligned)
    float* A      = (float*)d_ws;          // N*128
    float* B      = A + (size_t)N * F;     // N*128
    float* dis    = B + (size_t)N * F;     // N
    int*  counts  = (int*)(dis + N);       // N        } zeroed
    int*  fillc   = counts + N;            // N        } zeroed
    int*  flag    = fillc + N;             // 2 (pad)  } zeroed
    int*  row_ptr = flag + 2;              // N+2 (padded even)
    int*  bsum    = row_ptr + N + 2;       // NB (<=64 padded)
    int*  boff    = bsum + 64;             // 64
    int2* edata   = (int2*)(boff + 64);    // E

    hipMemsetAsync(counts, 0, (size_t)(2 * N + 2) * sizeof(int), stream);

    detect_kernel<<<CDIV(E, 256), 256, 0, stream>>>(edges, flag, E);
    count_kernel<<<CDIV(E, 256), 256, 0, stream>>>(edges, flag, counts, E);
    dis_kernel<<<CDIV(N, 256), 256, 0, stream>>>(counts, dis, N);
    scan1_kernel<<<NB, 256, 0, stream>>>(counts, bsum, N);
    scan2_kernel<<<1, 64, 0, stream>>>(bsum, boff, NB, row_ptr, N, E);
    scan3_kernel<<<NB, 256, 0, stream>>>(counts, boff, row_ptr, N);
    fill_kernel<<<CDIV(E, 256), 256, 0, stream>>>(edges, flag, row_ptr, fillc, dis, edata, E);

    // layer 1
    gemm_kernel<<<CDIV(N, 64), 256, 0, stream>>>(x, W1, A, N);
    agg_kernel<<<CDIV(N * 64, 256), 256, 0, stream>>>(A, row_ptr, edata, dis, b1, B, N);
    // layer 2
    gemm_kernel<<<CDIV(N, 64), 256, 0, stream>>>(B, W2, A, N);
    agg_kernel<<<CDIV(N * 64, 256), 256, 0, stream>>>(A, row_ptr, edata, dis, b2, out, N);
}

// Round 3
// 271.186 us; speedup vs baseline: 1.6793x; 1.2760x over previous
//
#include <hip/hip_runtime.h>
#include <hip/hip_bf16.h>

#define CDIV(a,b) (((a)+(b)-1)/(b))

__device__ __forceinline__ unsigned short f2bf(float f) {   // fp32 -> bf16 RNE
    unsigned u = __float_as_uint(f);
    return (unsigned short)((u + 0x7fff + ((u >> 16) & 1)) >> 16);
}
__device__ __forceinline__ float bf2f(unsigned short s) {
    return __uint_as_float(((unsigned)s) << 16);
}

// ---------------------------------------------------------------------------
// Layout detect (sampled): int64 little-endian => odd 32-bit words all 0.
// 4096 random values in [0,50000) are ~surely nonzero somewhere if int32.
// ---------------------------------------------------------------------------
__global__ void detect_kernel(const int* __restrict__ edges, int* __restrict__ flag, int E) {
    int n = min(E, 4096);
    int found = 0;
    for (int j = threadIdx.x; j < n; j += 256) found |= (edges[2 * j + 1] != 0);
    if (found) *flag = 1;   // benign race
}

__device__ __forceinline__ int load_src(const int* e, int f, int E, int i) {
    return f ? e[i] : e[2 * i];
}
__device__ __forceinline__ int load_dst(const int* e, int f, int E, int i) {
    return f ? e[E + i] : e[2 * (E + i)];
}

// degree count; also records each edge's arrival rank so fill needs no atomic
__global__ void count_kernel(const int* __restrict__ edges, const int* __restrict__ flag,
                             int* __restrict__ counts, int* __restrict__ rank, int E) {
    int e = blockIdx.x * blockDim.x + threadIdx.x;
    if (e >= E) return;
    int f = *flag;
    int d = load_dst(edges, f, E, e);
    rank[e] = atomicAdd(&counts[d], 1);
}

__global__ void dis_kernel(const int* __restrict__ counts, float* __restrict__ dis, int N) {
    int i = blockIdx.x * blockDim.x + threadIdx.x;
    if (i < N) dis[i] = rsqrtf((float)(counts[i] + 1));   // +1 = self-loop
}

// ---------------------------------------------------------------------------
// Multi-block exclusive scan: counts[0..N) -> row_ptr[0..N), row_ptr[N]=E.
// ---------------------------------------------------------------------------
__global__ __launch_bounds__(256) void scan1_kernel(const int* __restrict__ counts,
                                                    int* __restrict__ bsum, int N) {
    __shared__ int red[4];
    int tid = threadIdx.x;
    int base = blockIdx.x * 1024;
    int s = 0;
    #pragma unroll
    for (int j = 0; j < 4; ++j) {
        int idx = base + tid + j * 256;
        if (idx < N) s += counts[idx];
    }
    #pragma unroll
    for (int off = 32; off >= 1; off >>= 1) s += __shfl_down(s, off, 64);
    if ((tid & 63) == 0) red[tid >> 6] = s;
    __syncthreads();
    if (tid == 0) bsum[blockIdx.x] = red[0] + red[1] + red[2] + red[3];
}

__global__ void scan2_kernel(const int* __restrict__ bsum, int* __restrict__ boff,
                             int B, int* __restrict__ row_ptr, int N, int E) {
    int lane = threadIdx.x;
    int carry = 0;
    for (int base = 0; base < B; base += 64) {
        int i = base + lane;
        int v = (i < B) ? bsum[i] : 0;
        int x = v;
        #pragma unroll
        for (int off = 1; off < 64; off <<= 1) {
            int t = __shfl_up(x, off, 64);
            if (lane >= off) x += t;
        }
        if (i < B) boff[i] = carry + x - v;
        carry += __shfl(x, 63, 64);
    }
    if (lane == 0) row_ptr[N] = E;
}

__global__ __launch_bounds__(256) void scan3_kernel(const int* __restrict__ counts,
                                                    const int* __restrict__ boff,
                                                    int* __restrict__ row_ptr, int N) {
    __shared__ int wsum[4];
    int tid = threadIdx.x;
    int lane = tid & 63, wv = tid >> 6;
    int base = blockIdx.x * 1024 + tid * 4;
    int c[4];
    #pragma unroll
    for (int j = 0; j < 4; ++j) c[j] = (base + j < N) ? counts[base + j] : 0;
    int tsum = c[0] + c[1] + c[2] + c[3];
    int x = tsum;
    #pragma unroll
    for (int off = 1; off < 64; off <<= 1) {
        int t = __shfl_up(x, off, 64);
        if (lane >= off) x += t;
    }
    int texcl = x - tsum;
    if (lane == 63) wsum[wv] = x;
    __syncthreads();
    int woff = 0;
    for (int w = 0; w < wv; ++w) woff += wsum[w];
    int off0 = boff[blockIdx.x] + woff + texcl;
    int run = 0;
    #pragma unroll
    for (int j = 0; j < 4; ++j) {
        if (base + j < N) row_ptr[base + j] = off0 + run;
        run += c[j];
    }
}

// CSR fill (atomic-free): pos = row_ptr[dst] + rank. Packs (src, dis[src]).
__global__ void fill_kernel(const int* __restrict__ edges, const int* __restrict__ flag,
                            const int* __restrict__ row_ptr, const int* __restrict__ rank,
                            const float* __restrict__ dis, int2* __restrict__ edata, int E) {
    int e = blockIdx.x * blockDim.x + threadIdx.x;
    if (e >= E) return;
    int f = *flag;
    int s = load_src(edges, f, E, e);
    int d = load_dst(edges, f, E, e);
    edata[row_ptr[d] + rank[e]] = make_int2(s, __float_as_int(dis[s]));
}

// ---------------------------------------------------------------------------
// fp32 GEMM, bf16 output: out16[N,128] = bf16( X[N,128] @ W[128,128] )
// ---------------------------------------------------------------------------
__global__ __launch_bounds__(256) void gemm_kernel(const float* __restrict__ X,
                                                   const float* __restrict__ W,
                                                   unsigned short* __restrict__ out16, int N) {
    __shared__ float Xs[64][32];
    __shared__ float Ws[32][132];
    int tid = threadIdx.x;
    int tx = tid & 15;
    int ty = tid >> 4;
    int row0 = blockIdx.x * 64;
    float acc[4][8];
    #pragma unroll
    for (int i = 0; i < 4; ++i)
        #pragma unroll
        for (int j = 0; j < 8; ++j) acc[i][j] = 0.f;

    for (int kt = 0; kt < 128; kt += 32) {
        #pragma unroll
        for (int it = 0; it < 2; ++it) {
            int f = tid + it * 256;
            int r = f >> 3;
            int c4 = f & 7;
            float4 v = make_float4(0.f, 0.f, 0.f, 0.f);
            int gr = row0 + r;
            if (gr < N) v = *(const float4*)(X + (size_t)gr * 128 + kt + c4 * 4);
            *(float4*)(&Xs[r][c4 * 4]) = v;
        }
        #pragma unroll
        for (int it = 0; it < 4; ++it) {
            int f = tid + it * 256;
            int r = f >> 5;
            int c4 = f & 31;
            float4 v = *(const float4*)(W + (size_t)(kt + r) * 128 + c4 * 4);
            *(float4*)(&Ws[r][c4 * 4]) = v;
        }
        __syncthreads();
        #pragma unroll
        for (int k4 = 0; k4 < 32; k4 += 4) {
            float4 xv[4];
            #pragma unroll
            for (int i = 0; i < 4; ++i)
                xv[i] = *(const float4*)(&Xs[ty * 4 + i][k4]);
            #pragma unroll
            for (int q = 0; q < 4; ++q) {
                float4 wa = *(const float4*)(&Ws[k4 + q][tx * 8]);
                float4 wb = *(const float4*)(&Ws[k4 + q][tx * 8 + 4]);
                #pragma unroll
                for (int i = 0; i < 4; ++i) {
                    float xs = (q == 0) ? xv[i].x : (q == 1) ? xv[i].y
                             : (q == 2) ? xv[i].z : xv[i].w;
                    acc[i][0] += xs * wa.x; acc[i][1] += xs * wa.y;
                    acc[i][2] += xs * wa.z; acc[i][3] += xs * wa.w;
                    acc[i][4] += xs * wb.x; acc[i][5] += xs * wb.y;
                    acc[i][6] += xs * wb.z; acc[i][7] += xs * wb.w;
                }
            }
        }
        __syncthreads();
    }
    #pragma unroll
    for (int i = 0; i < 4; ++i) {
        int gr = row0 + ty * 4 + i;
        if (gr < N) {
            union { unsigned short us[8]; uint4 v; } pk;
            #pragma unroll
            for (int j = 0; j < 8; ++j) pk.us[j] = f2bf(acc[i][j]);
            *(uint4*)(out16 + (size_t)gr * 128 + tx * 8) = pk.v;
        }
    }
}

// ---------------------------------------------------------------------------
// Aggregation: one wave per node, bf16x2 (4B)/lane gathers, fp32 accumulate.
// Edge loop unrolled x8 with masked batches (invalid slots alias edata[e],
// weight 0) so the MLP stays 8 gathers deep with no extra traffic.
// ---------------------------------------------------------------------------
__global__ __launch_bounds__(256) void agg_kernel(const unsigned short* __restrict__ H16,
                                                  const int* __restrict__ row_ptr,
                                                  const int2* __restrict__ edata,
                                                  const float* __restrict__ dis,
                                                  const float* __restrict__ bias,
                                                  float* __restrict__ out, int N) {
    int wid = (blockIdx.x * blockDim.x + threadIdx.x) >> 6;
    int lane = threadIdx.x & 63;
    if (wid >= N) return;
    const ushort2* H2 = (const ushort2*)H16;
    float dd = dis[wid];
    ushort2 hv = H2[(size_t)wid * 64 + lane];
    float wself = dd * dd;
    float2 acc = make_float2(bf2f(hv.x) * wself, bf2f(hv.y) * wself);
    int e0 = __builtin_amdgcn_readfirstlane(row_ptr[wid]);
    int e1 = __builtin_amdgcn_readfirstlane(row_ptr[wid + 1]);
    for (int e = e0; e < e1; e += 8) {
        int rem = e1 - e;
        int   sj[8];
        float wj[8];
        #pragma unroll
        for (int j = 0; j < 8; ++j) {
            bool valid = j < rem;
            int2 ed = edata[valid ? e + j : e];
            sj[j] = ed.x;
            wj[j] = valid ? __int_as_float(ed.y) * dd : 0.f;
        }
        ushort2 aj[8];
        #pragma unroll
        for (int j = 0; j < 8; ++j)
            aj[j] = H2[(size_t)sj[j] * 64 + lane];
        #pragma unroll
        for (int j = 0; j < 8; ++j) {
            acc.x += bf2f(aj[j].x) * wj[j];
            acc.y += bf2f(aj[j].y) * wj[j];
        }
    }
    float2 b = ((const float2*)bias)[lane];
    float2 o = make_float2(fmaxf(acc.x + b.x, 0.f), fmaxf(acc.y + b.y, 0.f));
    ((float2*)out)[(size_t)wid * 64 + lane] = o;
}

extern "C" void kernel_launch(void* const* d_in, const int* in_sizes, int n_in,
                              void* d_out, int out_size, void* d_ws, size_t ws_size,
                              hipStream_t stream) {
    const float* x    = (const float*)d_in[0];
    const int*  edges = (const int*)d_in[1];
    const float* W1   = (const float*)d_in[2];
    const float* b1   = (const float*)d_in[3];
    const float* W2   = (const float*)d_in[4];
    const float* b2   = (const float*)d_in[5];
    float* out = (float*)d_out;

    const int F = 128;
    const int N = in_sizes[0] / F;
    const int E = in_sizes[1] / 2;
    const int NB = CDIV(N, 1024);          // scan blocks (<=64 assumed for bsum pad)

    // workspace layout (edata kept 8B-aligned: all counts below are even)
    unsigned short* A16 = (unsigned short*)d_ws;     // N*128 bf16
    float* B      = (float*)(A16 + (size_t)N * F);   // N*128 fp32
    float* dis    = B + (size_t)N * F;               // N
    int*  counts  = (int*)(dis + N);                 // N    } zeroed
    int*  flag    = counts + N;                      // 2    } zeroed
    int*  row_ptr = flag + 2;                        // N+2
    int*  bsum    = row_ptr + N + 2;                 // 64
    int*  boff    = bsum + 64;                       // 64
    int*  rank    = boff + 64;                       // E
    int2* edata   = (int2*)(rank + E);               // E

    hipMemsetAsync(counts, 0, (size_t)(N + 2) * sizeof(int), stream);

    detect_kernel<<<1, 256, 0, stream>>>(edges, flag, E);
    count_kernel<<<CDIV(E, 256), 256, 0, stream>>>(edges, flag, counts, rank, E);
    dis_kernel<<<CDIV(N, 256), 256, 0, stream>>>(counts, dis, N);
    scan1_kernel<<<NB, 256, 0, stream>>>(counts, bsum, N);
    scan2_kernel<<<1, 64, 0, stream>>>(bsum, boff, NB, row_ptr, N, E);
    scan3_kernel<<<NB, 256, 0, stream>>>(counts, boff, row_ptr, N);
    fill_kernel<<<CDIV(E, 256), 256, 0, stream>>>(edges, flag, row_ptr, rank, dis, edata, E);

    // layer 1
    gemm_kernel<<<CDIV(N, 64), 256, 0, stream>>>(x, W1, A16, N);
    agg_kernel<<<CDIV(N * 64, 256), 256, 0, stream>>>(A16, row_ptr, edata, dis, b1, B, N);
    // layer 2
    gemm_kernel<<<CDIV(N, 64), 256, 0, stream>>>(B, W2, A16, N);
    agg_kernel<<<CDIV(N * 64, 256), 256, 0, stream>>>(A16, row_ptr, edata, dis, b2, out, N);
}

// Round 4
// 248.514 us; speedup vs baseline: 1.8326x; 1.0912x over previous
//
#include <hip/hip_runtime.h>
#include <hip/hip_bf16.h>

#define CDIV(a,b) (((a)+(b)-1)/(b))

typedef __bf16 bf16x8 __attribute__((ext_vector_type(8)));
typedef float  f32x4  __attribute__((ext_vector_type(4)));

union Frag16 { uint4 u; bf16x8 f; unsigned short s[8]; };
union Pack8  { unsigned short s[4]; uint2 u; };

__device__ __forceinline__ unsigned short f2bf(float f) {   // fp32 -> bf16 RNE
    unsigned u = __float_as_uint(f);
    return (unsigned short)((u + 0x7fff + ((u >> 16) & 1)) >> 16);
}
__device__ __forceinline__ float bf2f(unsigned short s) {
    return __uint_as_float(((unsigned)s) << 16);
}

// ---------------------------------------------------------------------------
// Layout detect (sampled): int64 little-endian => odd 32-bit words all 0.
// ---------------------------------------------------------------------------
__global__ void detect_kernel(const int* __restrict__ edges, int* __restrict__ flag, int E) {
    int n = min(E, 4096);
    int found = 0;
    for (int j = threadIdx.x; j < n; j += 256) found |= (edges[2 * j + 1] != 0);
    if (found) *flag = 1;   // benign race
}

__device__ __forceinline__ int load_src(const int* e, int f, int E, int i) {
    return f ? e[i] : e[2 * i];
}
__device__ __forceinline__ int load_dst(const int* e, int f, int E, int i) {
    return f ? e[E + i] : e[2 * (E + i)];
}

// ---------------------------------------------------------------------------
// Degree count, sharded 8x by blockIdx&7 to cut same-address atomic
// contention (16 -> 2 avg ops/addr). rank packs (local_rank<<3)|shard.
// ---------------------------------------------------------------------------
__global__ void count_kernel(const int* __restrict__ edges, const int* __restrict__ flag,
                             int* __restrict__ counts_sh, int* __restrict__ rank,
                             int E, int N) {
    int e = blockIdx.x * blockDim.x + threadIdx.x;
    if (e >= E) return;
    int f = *flag;
    int d = load_dst(edges, f, E, e);
    int s = blockIdx.x & 7;
    int r = atomicAdd(&counts_sh[s * N + d], 1);
    rank[e] = (r << 3) | s;
}

// per-node: turn shard counts into shard base offsets; total -> counts[d]
__global__ void merge_kernel(int* __restrict__ counts_sh, int* __restrict__ counts, int N) {
    int d = blockIdx.x * blockDim.x + threadIdx.x;
    if (d >= N) return;
    int run = 0;
    #pragma unroll
    for (int s = 0; s < 8; ++s) {
        int v = counts_sh[s * N + d];
        counts_sh[s * N + d] = run;
        run += v;
    }
    counts[d] = run;
}

__global__ void dis_kernel(const int* __restrict__ counts, float* __restrict__ dis, int N) {
    int i = blockIdx.x * blockDim.x + threadIdx.x;
    if (i < N) dis[i] = rsqrtf((float)(counts[i] + 1));   // +1 = self-loop
}

// ---------------------------------------------------------------------------
// Multi-block exclusive scan: counts[0..N) -> row_ptr[0..N), row_ptr[N]=E.
// ---------------------------------------------------------------------------
__global__ __launch_bounds__(256) void scan1_kernel(const int* __restrict__ counts,
                                                    int* __restrict__ bsum, int N) {
    __shared__ int red[4];
    int tid = threadIdx.x;
    int base = blockIdx.x * 1024;
    int s = 0;
    #pragma unroll
    for (int j = 0; j < 4; ++j) {
        int idx = base + tid + j * 256;
        if (idx < N) s += counts[idx];
    }
    #pragma unroll
    for (int off = 32; off >= 1; off >>= 1) s += __shfl_down(s, off, 64);
    if ((tid & 63) == 0) red[tid >> 6] = s;
    __syncthreads();
    if (tid == 0) bsum[blockIdx.x] = red[0] + red[1] + red[2] + red[3];
}

__global__ void scan2_kernel(const int* __restrict__ bsum, int* __restrict__ boff,
                             int B, int* __restrict__ row_ptr, int N, int E) {
    int lane = threadIdx.x;
    int carry = 0;
    for (int base = 0; base < B; base += 64) {
        int i = base + lane;
        int v = (i < B) ? bsum[i] : 0;
        int x = v;
        #pragma unroll
        for (int off = 1; off < 64; off <<= 1) {
            int t = __shfl_up(x, off, 64);
            if (lane >= off) x += t;
        }
        if (i < B) boff[i] = carry + x - v;
        carry += __shfl(x, 63, 64);
    }
    if (lane == 0) row_ptr[N] = E;
}

__global__ __launch_bounds__(256) void scan3_kernel(const int* __restrict__ counts,
                                                    const int* __restrict__ boff,
                                                    int* __restrict__ row_ptr, int N) {
    __shared__ int wsum[4];
    int tid = threadIdx.x;
    int lane = tid & 63, wv = tid >> 6;
    int base = blockIdx.x * 1024 + tid * 4;
    int c[4];
    #pragma unroll
    for (int j = 0; j < 4; ++j) c[j] = (base + j < N) ? counts[base + j] : 0;
    int tsum = c[0] + c[1] + c[2] + c[3];
    int x = tsum;
    #pragma unroll
    for (int off = 1; off < 64; off <<= 1) {
        int t = __shfl_up(x, off, 64);
        if (lane >= off) x += t;
    }
    int texcl = x - tsum;
    if (lane == 63) wsum[wv] = x;
    __syncthreads();
    int woff = 0;
    for (int w = 0; w < wv; ++w) woff += wsum[w];
    int off0 = boff[blockIdx.x] + woff + texcl;
    int run = 0;
    #pragma unroll
    for (int j = 0; j < 4; ++j) {
        if (base + j < N) row_ptr[base + j] = off0 + run;
        run += c[j];
    }
}

// CSR fill (atomic-free): pos = row_ptr[d] + shard_base + local_rank.
__global__ void fill_kernel(const int* __restrict__ edges, const int* __restrict__ flag,
                            const int* __restrict__ row_ptr, const int* __restrict__ rank,
                            const int* __restrict__ counts_sh,
                            const float* __restrict__ dis, int2* __restrict__ edata,
                            int E, int N) {
    int e = blockIdx.x * blockDim.x + threadIdx.x;
    if (e >= E) return;
    int f = *flag;
    int s = load_src(edges, f, E, e);
    int d = load_dst(edges, f, E, e);
    int rk = rank[e];
    int sh = rk & 7;
    int pos = row_ptr[d] + counts_sh[sh * N + d] + (rk >> 3);
    edata[pos] = make_int2(s, __float_as_int(dis[s]));
}

// ---------------------------------------------------------------------------
// W pre-swizzle: W[128][128] fp32 -> hi/lo bf16 MFMA B-fragments.
// Fragment order: chunk c = (ntile*4 + kstep)*64 + lane, 8 bf16 per chunk:
//   B[k = kstep*32 + (lane>>4)*8 + j][n = ntile*16 + (lane&15)]
// ---------------------------------------------------------------------------
__global__ __launch_bounds__(256) void wprep_kernel(const float* __restrict__ W,
                                                    unsigned short* __restrict__ Wfh,
                                                    unsigned short* __restrict__ Wfl) {
    __shared__ float Wld[128][128];   // 64 KB
    int tid = threadIdx.x;
    #pragma unroll
    for (int it = 0; it < 16; ++it) {
        int f = it * 256 + tid;
        int r = f >> 5, c4 = f & 31;
        *(float4*)(&Wld[r][c4 * 4]) = *(const float4*)(W + r * 128 + c4 * 4);
    }
    __syncthreads();
    #pragma unroll
    for (int it = 0; it < 8; ++it) {
        int c = it * 256 + tid;           // chunk in [0, 2048)
        int ntk = c >> 6;                 // (ntile*4 + kstep)
        int lane = c & 63;
        int ks = ntk & 3;
        int ntile = ntk >> 2;
        int quad = lane >> 4, nlo = lane & 15;
        int n = ntile * 16 + nlo;
        Frag16 h, l;
        #pragma unroll
        for (int j = 0; j < 8; ++j) {
            float w = Wld[ks * 32 + quad * 8 + j][n];
            h.s[j] = f2bf(w);
            float rr = w - bf2f(h.s[j]);
            l.s[j] = f2bf(rr);
        }
        *(uint4*)(Wfh + (size_t)c * 8) = h.u;
        *(uint4*)(Wfl + (size_t)c * 8) = l.u;
    }
}

// ---------------------------------------------------------------------------
// Split-bf16 MFMA GEMM: out16 = bf16( X[N,128] @ W[128,128] ), fp32-accurate
// via xh*wh + xh*wl + xl*wh (lo*lo term ~2^-18, negligible).
// Block = 4 waves = 64 rows; each wave: 16-row strip x 128 cols.
// ---------------------------------------------------------------------------
__global__ __launch_bounds__(256) void gemm_mfma_kernel(const float* __restrict__ X,
                                                        const unsigned short* __restrict__ Wfh,
                                                        const unsigned short* __restrict__ Wfl,
                                                        unsigned short* __restrict__ out16,
                                                        int N) {
    __shared__ unsigned short Xh[64][136];   // +8 pad: 2-way LDS conflicts only
    __shared__ unsigned short Xl[64][136];
    int tid = threadIdx.x;
    int row0 = blockIdx.x * 64;
    // stage X -> hi/lo bf16
    #pragma unroll
    for (int it = 0; it < 8; ++it) {
        int f = it * 256 + tid;           // 2048 float4 chunks
        int r = f >> 5, c4 = f & 31;
        float4 v = make_float4(0.f, 0.f, 0.f, 0.f);
        int gr = row0 + r;
        if (gr < N) v = *(const float4*)(X + (size_t)gr * 128 + c4 * 4);
        float vv[4] = {v.x, v.y, v.z, v.w};
        Pack8 h, l;
        #pragma unroll
        for (int j = 0; j < 4; ++j) {
            h.s[j] = f2bf(vv[j]);
            float rr = vv[j] - bf2f(h.s[j]);
            l.s[j] = f2bf(rr);
        }
        *(uint2*)(&Xh[r][c4 * 4]) = h.u;
        *(uint2*)(&Xl[r][c4 * 4]) = l.u;
    }
    __syncthreads();

    int lane = tid & 63;
    int wv = tid >> 6;
    int quad = lane >> 4, nlo = lane & 15;
    f32x4 acc[8];
    #pragma unroll
    for (int t = 0; t < 8; ++t) acc[t] = (f32x4){0.f, 0.f, 0.f, 0.f};

    #pragma unroll
    for (int ks = 0; ks < 4; ++ks) {
        int kcol = ks * 32 + quad * 8;
        Frag16 xh, xl;
        xh.u = *(const uint4*)(&Xh[wv * 16 + nlo][kcol]);
        xl.u = *(const uint4*)(&Xl[wv * 16 + nlo][kcol]);
        #pragma unroll
        for (int t = 0; t < 8; ++t) {
            size_t cidx = ((size_t)(t * 4 + ks) * 64 + lane) * 8;
            Frag16 wh, wl;
            wh.u = *(const uint4*)(Wfh + cidx);
            wl.u = *(const uint4*)(Wfl + cidx);
            acc[t] = __builtin_amdgcn_mfma_f32_16x16x32_bf16(xh.f, wh.f, acc[t], 0, 0, 0);
            acc[t] = __builtin_amdgcn_mfma_f32_16x16x32_bf16(xh.f, wl.f, acc[t], 0, 0, 0);
            acc[t] = __builtin_amdgcn_mfma_f32_16x16x32_bf16(xl.f, wh.f, acc[t], 0, 0, 0);
        }
    }
    // epilogue: C/D layout col=lane&15, row=quad*4+reg
    #pragma unroll
    for (int rg = 0; rg < 4; ++rg) {
        int gr = row0 + wv * 16 + quad * 4 + rg;
        if (gr < N) {
            #pragma unroll
            for (int t = 0; t < 8; ++t)
                out16[(size_t)gr * 128 + t * 16 + nlo] = f2bf(acc[t][rg]);
        }
    }
}

// ---------------------------------------------------------------------------
// Aggregation: one wave per node, bf16x2 (4B)/lane gathers, fp32 accumulate.
// ---------------------------------------------------------------------------
__global__ __launch_bounds__(256) void agg_kernel(const unsigned short* __restrict__ H16,
                                                  const int* __restrict__ row_ptr,
                                                  const int2* __restrict__ edata,
                                                  const float* __restrict__ dis,
                                                  const float* __restrict__ bias,
                                                  float* __restrict__ out, int N) {
    int wid = (blockIdx.x * blockDim.x + threadIdx.x) >> 6;
    int lane = threadIdx.x & 63;
    if (wid >= N) return;
    const ushort2* H2 = (const ushort2*)H16;
    float dd = dis[wid];
    ushort2 hv = H2[(size_t)wid * 64 + lane];
    float wself = dd * dd;
    float2 acc = make_float2(bf2f(hv.x) * wself, bf2f(hv.y) * wself);
    int e0 = __builtin_amdgcn_readfirstlane(row_ptr[wid]);
    int e1 = __builtin_amdgcn_readfirstlane(row_ptr[wid + 1]);
    for (int e = e0; e < e1; e += 8) {
        int rem = e1 - e;
        int   sj[8];
        float wj[8];
        #pragma unroll
        for (int j = 0; j < 8; ++j) {
            bool valid = j < rem;
            int2 ed = edata[valid ? e + j : e];
            sj[j] = ed.x;
            wj[j] = valid ? __int_as_float(ed.y) * dd : 0.f;
        }
        ushort2 aj[8];
        #pragma unroll
        for (int j = 0; j < 8; ++j)
            aj[j] = H2[(size_t)sj[j] * 64 + lane];
        #pragma unroll
        for (int j = 0; j < 8; ++j) {
            acc.x += bf2f(aj[j].x) * wj[j];
            acc.y += bf2f(aj[j].y) * wj[j];
        }
    }
    float2 b = ((const float2*)bias)[lane];
    float2 o = make_float2(fmaxf(acc.x + b.x, 0.f), fmaxf(acc.y + b.y, 0.f));
    ((float2*)out)[(size_t)wid * 64 + lane] = o;
}

extern "C" void kernel_launch(void* const* d_in, const int* in_sizes, int n_in,
                              void* d_out, int out_size, void* d_ws, size_t ws_size,
                              hipStream_t stream) {
    const float* x    = (const float*)d_in[0];
    const int*  edges = (const int*)d_in[1];
    const float* W1   = (const float*)d_in[2];
    const float* b1   = (const float*)d_in[3];
    const float* W2   = (const float*)d_in[4];
    const float* b2   = (const float*)d_in[5];
    float* out = (float*)d_out;

    const int F = 128;
    const int N = in_sizes[0] / F;
    const int E = in_sizes[1] / 2;
    const int NB = CDIV(N, 1024);          // scan blocks

    #define AL4(v) (((v) + 3) & ~3)        // keep every segment 16B-aligned
    unsigned short* A16 = (unsigned short*)d_ws;            // N*128 bf16
    float* B        = (float*)(A16 + (size_t)AL4(N * F));   // N*128 fp32
    float* dis      = B + (size_t)AL4(N * F);               // N
    int*  counts    = (int*)(dis + AL4(N));                 // N
    int*  counts_sh = counts + AL4(N);                      // 8N   } zeroed (with counts? no: alone)
    int*  flag      = counts_sh + AL4(8 * N);               // 4    } zeroed
    int*  row_ptr   = flag + 4;                             // N+4
    int*  bsum      = row_ptr + AL4(N + 1);                 // 64
    int*  boff      = bsum + 64;                            // 64
    int*  rank      = boff + 64;                            // E
    int2* edata     = (int2*)(rank + AL4(E));               // E
    unsigned short* Wf1h = (unsigned short*)(edata + E);    // 16384 each
    unsigned short* Wf1l = Wf1h + 16384;
    unsigned short* Wf2h = Wf1l + 16384;
    unsigned short* Wf2l = Wf2h + 16384;

    // zero counts + counts_sh + flag (contiguous)
    size_t zero_ints = (size_t)AL4(N) + AL4(8 * N) + 4;
    hipMemsetAsync(counts, 0, zero_ints * sizeof(int), stream);

    detect_kernel<<<1, 256, 0, stream>>>(edges, flag, E);
    count_kernel<<<CDIV(E, 256), 256, 0, stream>>>(edges, flag, counts_sh, rank, E, N);
    merge_kernel<<<CDIV(N, 256), 256, 0, stream>>>(counts_sh, counts, N);
    dis_kernel<<<CDIV(N, 256), 256, 0, stream>>>(counts, dis, N);
    scan1_kernel<<<NB, 256, 0, stream>>>(counts, bsum, N);
    scan2_kernel<<<1, 64, 0, stream>>>(bsum, boff, NB, row_ptr, N, E);
    scan3_kernel<<<NB, 256, 0, stream>>>(counts, boff, row_ptr, N);
    fill_kernel<<<CDIV(E, 256), 256, 0, stream>>>(edges, flag, row_ptr, rank,
                                                  counts_sh, dis, edata, E, N);
    wprep_kernel<<<1, 256, 0, stream>>>(W1, Wf1h, Wf1l);
    wprep_kernel<<<1, 256, 0, stream>>>(W2, Wf2h, Wf2l);

    // layer 1
    gemm_mfma_kernel<<<CDIV(N, 64), 256, 0, stream>>>(x, Wf1h, Wf1l, A16, N);
    agg_kernel<<<CDIV(N * 64, 256), 256, 0, stream>>>(A16, row_ptr, edata, dis, b1, B, N);
    // layer 2
    gemm_mfma_kernel<<<CDIV(N, 64), 256, 0, stream>>>(B, Wf2h, Wf2l, A16, N);
    agg_kernel<<<CDIV(N * 64, 256), 256, 0, stream>>>(A16, row_ptr, edata, dis, b2, out, N);
}

// Round 5
// 229.544 us; speedup vs baseline: 1.9840x; 1.0826x over previous
//
#include <hip/hip_runtime.h>
#include <hip/hip_bf16.h>

#define CDIV(a,b) (((a)+(b)-1)/(b))

typedef __bf16 bf16x8 __attribute__((ext_vector_type(8)));
typedef float  f32x4  __attribute__((ext_vector_type(4)));

union Frag16 { uint4 u; bf16x8 f; unsigned short s[8]; };
union Pack8  { unsigned short s[4]; uint2 u; };

__device__ __forceinline__ unsigned short f2bf(float f) {   // fp32 -> bf16 RNE
    unsigned u = __float_as_uint(f);
    return (unsigned short)((u + 0x7fff + ((u >> 16) & 1)) >> 16);
}
__device__ __forceinline__ float bf2f(unsigned short s) {
    return __uint_as_float(((unsigned)s) << 16);
}

__device__ __forceinline__ int load_src(const int* e, int f, int E, int i) {
    return f ? e[i] : e[2 * i];
}
__device__ __forceinline__ int load_dst(const int* e, int f, int E, int i) {
    return f ? e[E + i] : e[2 * (E + i)];
}

// ---------------------------------------------------------------------------
// prep: blocks 0,1 swizzle W1/W2 into hi/lo bf16 MFMA B-fragments (LDS-free,
// L2-served strided reads); block 2 samples edge layout (int64 LE => odd
// words all zero).  Fragment order: chunk c=(ntile*4+ks)*64+lane, 8 bf16:
//   B[k = ks*32 + (lane>>4)*8 + j][n = ntile*16 + (lane&15)]
// ---------------------------------------------------------------------------
__global__ __launch_bounds__(256) void prep_kernel(const float* __restrict__ W1,
                                                   const float* __restrict__ W2,
                                                   unsigned short* __restrict__ Wf1h,
                                                   unsigned short* __restrict__ Wf1l,
                                                   unsigned short* __restrict__ Wf2h,
                                                   unsigned short* __restrict__ Wf2l,
                                                   const int* __restrict__ edges,
                                                   int* __restrict__ flag, int E) {
    int tid = threadIdx.x;
    if (blockIdx.x == 2) {
        int n = min(E, 4096);
        int found = 0;
        for (int j = tid; j < n; j += 256) found |= (edges[2 * j + 1] != 0);
        if (found) *flag = 1;   // benign race
        return;
    }
    const float* W = (blockIdx.x == 0) ? W1 : W2;
    unsigned short* Wfh = (blockIdx.x == 0) ? Wf1h : Wf2h;
    unsigned short* Wfl = (blockIdx.x == 0) ? Wf1l : Wf2l;
    #pragma unroll
    for (int it = 0; it < 8; ++it) {
        int c = it * 256 + tid;           // chunk in [0, 2048)
        int ntk = c >> 6;
        int lane = c & 63;
        int ks = ntk & 3;
        int ntile = ntk >> 2;
        int quad = lane >> 4, nlo = lane & 15;
        int n = ntile * 16 + nlo;
        Frag16 h, l;
        #pragma unroll
        for (int j = 0; j < 8; ++j) {
            float w = W[(ks * 32 + quad * 8 + j) * 128 + n];
            h.s[j] = f2bf(w);
            float rr = w - bf2f(h.s[j]);
            l.s[j] = f2bf(rr);
        }
        *(uint4*)(Wfh + (size_t)c * 8) = h.u;
        *(uint4*)(Wfl + (size_t)c * 8) = l.u;
    }
}

// ---------------------------------------------------------------------------
// Split-bf16 MFMA GEMM body: out16 = bf16( X[N,128] @ W[128,128] ),
// fp32-accurate via xh*wh + xh*wl + xl*wh.  64 rows/block, 4 waves.
// ---------------------------------------------------------------------------
__device__ __forceinline__ void gemm_body(const float* __restrict__ X,
                                          const unsigned short* __restrict__ Wfh,
                                          const unsigned short* __restrict__ Wfl,
                                          unsigned short* __restrict__ out16,
                                          int N, int blk,
                                          unsigned short (*Xh)[136],
                                          unsigned short (*Xl)[136]) {
    int tid = threadIdx.x;
    int row0 = blk * 64;
    #pragma unroll
    for (int it = 0; it < 8; ++it) {
        int f = it * 256 + tid;           // 2048 float4 chunks
        int r = f >> 5, c4 = f & 31;
        float4 v = make_float4(0.f, 0.f, 0.f, 0.f);
        int gr = row0 + r;
        if (gr < N) v = *(const float4*)(X + (size_t)gr * 128 + c4 * 4);
        float vv[4] = {v.x, v.y, v.z, v.w};
        Pack8 h, l;
        #pragma unroll
        for (int j = 0; j < 4; ++j) {
            h.s[j] = f2bf(vv[j]);
            float rr = vv[j] - bf2f(h.s[j]);
            l.s[j] = f2bf(rr);
        }
        *(uint2*)(&Xh[r][c4 * 4]) = h.u;
        *(uint2*)(&Xl[r][c4 * 4]) = l.u;
    }
    __syncthreads();

    int lane = tid & 63;
    int wv = tid >> 6;
    int quad = lane >> 4, nlo = lane & 15;
    f32x4 acc[8];
    #pragma unroll
    for (int t = 0; t < 8; ++t) acc[t] = (f32x4){0.f, 0.f, 0.f, 0.f};

    #pragma unroll
    for (int ks = 0; ks < 4; ++ks) {
        int kcol = ks * 32 + quad * 8;
        Frag16 xh, xl;
        xh.u = *(const uint4*)(&Xh[wv * 16 + nlo][kcol]);
        xl.u = *(const uint4*)(&Xl[wv * 16 + nlo][kcol]);
        #pragma unroll
        for (int t = 0; t < 8; ++t) {
            size_t cidx = ((size_t)(t * 4 + ks) * 64 + lane) * 8;
            Frag16 wh, wl;
            wh.u = *(const uint4*)(Wfh + cidx);
            wl.u = *(const uint4*)(Wfl + cidx);
            acc[t] = __builtin_amdgcn_mfma_f32_16x16x32_bf16(xh.f, wh.f, acc[t], 0, 0, 0);
            acc[t] = __builtin_amdgcn_mfma_f32_16x16x32_bf16(xh.f, wl.f, acc[t], 0, 0, 0);
            acc[t] = __builtin_amdgcn_mfma_f32_16x16x32_bf16(xl.f, wh.f, acc[t], 0, 0, 0);
        }
    }
    // C/D layout: col = lane&15, row = quad*4 + reg
    #pragma unroll
    for (int rg = 0; rg < 4; ++rg) {
        int gr = row0 + wv * 16 + quad * 4 + rg;
        if (gr < N) {
            #pragma unroll
            for (int t = 0; t < 8; ++t)
                out16[(size_t)gr * 128 + t * 16 + nlo] = f2bf(acc[t][rg]);
        }
    }
}

// ---------------------------------------------------------------------------
// FAT kernel: blocks [0,Ggemm) do layer-1 GEMM (x@W1 -> A16); the rest do the
// sharded degree count (atomics).  Independent inputs; MFMA pipe and atomic
// pipe overlap across blocks on the same CU.
// ---------------------------------------------------------------------------
__global__ __launch_bounds__(256) void fat_kernel(const float* __restrict__ X,
                                                  const unsigned short* __restrict__ Wfh,
                                                  const unsigned short* __restrict__ Wfl,
                                                  unsigned short* __restrict__ out16,
                                                  int N, int Ggemm,
                                                  const int* __restrict__ edges,
                                                  const int* __restrict__ flag,
                                                  int* __restrict__ counts_sh,
                                                  int* __restrict__ rank, int E) {
    __shared__ unsigned short Xh[64][136];   // +8 pad: 2-way conflicts only
    __shared__ unsigned short Xl[64][136];
    if (blockIdx.x < (unsigned)Ggemm) {
        gemm_body(X, Wfh, Wfl, out16, N, blockIdx.x, Xh, Xl);
        return;
    }
    int e = (blockIdx.x - Ggemm) * 256 + threadIdx.x;
    if (e >= E) return;
    int f = *flag;
    int d = load_dst(edges, f, E, e);
    int s = blockIdx.x & 7;
    int r = atomicAdd(&counts_sh[s * N + d], 1);
    rank[e] = (r << 3) | s;
}

// standalone GEMM for layer 2
__global__ __launch_bounds__(256) void gemm_mfma_kernel(const float* __restrict__ X,
                                                        const unsigned short* __restrict__ Wfh,
                                                        const unsigned short* __restrict__ Wfl,
                                                        unsigned short* __restrict__ out16,
                                                        int N) {
    __shared__ unsigned short Xh[64][136];
    __shared__ unsigned short Xl[64][136];
    gemm_body(X, Wfh, Wfl, out16, N, blockIdx.x, Xh, Xl);
}

// ---------------------------------------------------------------------------
// merge_dis: per node, shard counts -> shard base offsets (in place), total
// degree -> counts, dis = rsqrt(deg+1); per-1024-node sums -> bsum (scan1).
// ---------------------------------------------------------------------------
__global__ __launch_bounds__(256) void merge_dis_kernel(int* __restrict__ counts_sh,
                                                        int* __restrict__ counts,
                                                        float* __restrict__ dis,
                                                        int* __restrict__ bsum, int N) {
    __shared__ int red[4];
    int tid = threadIdx.x;
    int bs = 0;
    #pragma unroll
    for (int j = 0; j < 4; ++j) {
        int d = blockIdx.x * 1024 + j * 256 + tid;
        if (d < N) {
            int run = 0;
            #pragma unroll
            for (int s = 0; s < 8; ++s) {
                int v = counts_sh[s * N + d];
                counts_sh[s * N + d] = run;
                run += v;
            }
            counts[d] = run;
            dis[d] = rsqrtf((float)(run + 1));
            bs += run;
        }
    }
    #pragma unroll
    for (int off = 32; off >= 1; off >>= 1) bs += __shfl_down(bs, off, 64);
    if ((tid & 63) == 0) red[tid >> 6] = bs;
    __syncthreads();
    if (tid == 0) bsum[blockIdx.x] = red[0] + red[1] + red[2] + red[3];
}

__global__ void scan2_kernel(const int* __restrict__ bsum, int* __restrict__ boff,
                             int B, int* __restrict__ row_ptr, int N, int E) {
    int lane = threadIdx.x;
    int carry = 0;
    for (int base = 0; base < B; base += 64) {
        int i = base + lane;
        int v = (i < B) ? bsum[i] : 0;
        int x = v;
        #pragma unroll
        for (int off = 1; off < 64; off <<= 1) {
            int t = __shfl_up(x, off, 64);
            if (lane >= off) x += t;
        }
        if (i < B) boff[i] = carry + x - v;
        carry += __shfl(x, 63, 64);
    }
    if (lane == 0) row_ptr[N] = E;
}

__global__ __launch_bounds__(256) void scan3_kernel(const int* __restrict__ counts,
                                                    const int* __restrict__ boff,
                                                    int* __restrict__ row_ptr, int N) {
    __shared__ int wsum[4];
    int tid = threadIdx.x;
    int lane = tid & 63, wv = tid >> 6;
    int base = blockIdx.x * 1024 + tid * 4;
    int c[4];
    #pragma unroll
    for (int j = 0; j < 4; ++j) c[j] = (base + j < N) ? counts[base + j] : 0;
    int tsum = c[0] + c[1] + c[2] + c[3];
    int x = tsum;
    #pragma unroll
    for (int off = 1; off < 64; off <<= 1) {
        int t = __shfl_up(x, off, 64);
        if (lane >= off) x += t;
    }
    int texcl = x - tsum;
    if (lane == 63) wsum[wv] = x;
    __syncthreads();
    int woff = 0;
    for (int w = 0; w < wv; ++w) woff += wsum[w];
    int off0 = boff[blockIdx.x] + woff + texcl;
    int run = 0;
    #pragma unroll
    for (int j = 0; j < 4; ++j) {
        if (base + j < N) row_ptr[base + j] = off0 + run;
        run += c[j];
    }
}

// CSR fill (atomic-free): pos = row_ptr[d] + shard_base + local_rank.
__global__ void fill_kernel(const int* __restrict__ edges, const int* __restrict__ flag,
                            const int* __restrict__ row_ptr, const int* __restrict__ rank,
                            const int* __restrict__ counts_sh,
                            const float* __restrict__ dis, int2* __restrict__ edata,
                            int E, int N) {
    int e = blockIdx.x * blockDim.x + threadIdx.x;
    if (e >= E) return;
    int f = *flag;
    int s = load_src(edges, f, E, e);
    int d = load_dst(edges, f, E, e);
    int rk = rank[e];
    int sh = rk & 7;
    int pos = row_ptr[d] + counts_sh[sh * N + d] + (rk >> 3);
    edata[pos] = make_int2(s, __float_as_int(dis[s]));
}

// ---------------------------------------------------------------------------
// Aggregation: one wave per node, bf16x2 (4B)/lane gathers, fp32 accumulate.
// Edge loop unrolled x8 with masked batches (invalid slots alias edata[e],
// weight 0) to keep 8 gathers in flight with no extra traffic.
// ---------------------------------------------------------------------------
__global__ __launch_bounds__(256) void agg_kernel(const unsigned short* __restrict__ H16,
                                                  const int* __restrict__ row_ptr,
                                                  const int2* __restrict__ edata,
                                                  const float* __restrict__ dis,
                                                  const float* __restrict__ bias,
                                                  float* __restrict__ out, int N) {
    int wid = (blockIdx.x * blockDim.x + threadIdx.x) >> 6;
    int lane = threadIdx.x & 63;
    if (wid >= N) return;
    const ushort2* H2 = (const ushort2*)H16;
    float dd = dis[wid];
    ushort2 hv = H2[(size_t)wid * 64 + lane];
    float wself = dd * dd;
    float2 acc = make_float2(bf2f(hv.x) * wself, bf2f(hv.y) * wself);
    int e0 = __builtin_amdgcn_readfirstlane(row_ptr[wid]);
    int e1 = __builtin_amdgcn_readfirstlane(row_ptr[wid + 1]);
    for (int e = e0; e < e1; e += 8) {
        int rem = e1 - e;
        int   sj[8];
        float wj[8];
        #pragma unroll
        for (int j = 0; j < 8; ++j) {
            bool valid = j < rem;
            int2 ed = edata[valid ? e + j : e];
            sj[j] = ed.x;
            wj[j] = valid ? __int_as_float(ed.y) * dd : 0.f;
        }
        ushort2 aj[8];
        #pragma unroll
        for (int j = 0; j < 8; ++j)
            aj[j] = H2[(size_t)sj[j] * 64 + lane];
        #pragma unroll
        for (int j = 0; j < 8; ++j) {
            acc.x += bf2f(aj[j].x) * wj[j];
            acc.y += bf2f(aj[j].y) * wj[j];
        }
    }
    float2 b = ((const float2*)bias)[lane];
    float2 o = make_float2(fmaxf(acc.x + b.x, 0.f), fmaxf(acc.y + b.y, 0.f));
    ((float2*)out)[(size_t)wid * 64 + lane] = o;
}

extern "C" void kernel_launch(void* const* d_in, const int* in_sizes, int n_in,
                              void* d_out, int out_size, void* d_ws, size_t ws_size,
                              hipStream_t stream) {
    const float* x    = (const float*)d_in[0];
    const int*  edges = (const int*)d_in[1];
    const float* W1   = (const float*)d_in[2];
    const float* b1   = (const float*)d_in[3];
    const float* W2   = (const float*)d_in[4];
    const float* b2   = (const float*)d_in[5];
    float* out = (float*)d_out;

    const int F = 128;
    const int N = in_sizes[0] / F;
    const int E = in_sizes[1] / 2;
    const int NB = CDIV(N, 1024);          // scan blocks (<=64)
    const int Ggemm = CDIV(N, 64);
    const int Gcount = CDIV(E, 256);

    #define AL4(v) (((v) + 3) & ~3)        // keep segments 16B-aligned
    unsigned short* A16 = (unsigned short*)d_ws;            // N*128 bf16
    float* B        = (float*)(A16 + (size_t)AL4(N * F));   // N*128 fp32
    float* dis      = B + (size_t)AL4(N * F);               // N
    int*  counts    = (int*)(dis + AL4(N));                 // N (written by merge_dis)
    int*  counts_sh = counts + AL4(N);                      // 8N  } zeroed
    int*  flag      = counts_sh + AL4(8 * N);               // 4   } zeroed
    int*  row_ptr   = flag + 4;                             // N+4
    int*  bsum      = row_ptr + AL4(N + 1);                 // 64
    int*  boff      = bsum + 64;                            // 64
    int*  rank      = boff + 64;                            // E
    int2* edata     = (int2*)(rank + AL4(E));               // E
    unsigned short* Wf1h = (unsigned short*)(edata + E);    // 16384 each
    unsigned short* Wf1l = Wf1h + 16384;
    unsigned short* Wf2h = Wf1l + 16384;
    unsigned short* Wf2l = Wf2h + 16384;

    // zero counts_sh + flag (contiguous)
    hipMemsetAsync(counts_sh, 0, ((size_t)AL4(8 * N) + 4) * sizeof(int), stream);

    prep_kernel<<<3, 256, 0, stream>>>(W1, W2, Wf1h, Wf1l, Wf2h, Wf2l, edges, flag, E);
    fat_kernel<<<Ggemm + Gcount, 256, 0, stream>>>(x, Wf1h, Wf1l, A16, N, Ggemm,
                                                   edges, flag, counts_sh, rank, E);
    merge_dis_kernel<<<NB, 256, 0, stream>>>(counts_sh, counts, dis, bsum, N);
    scan2_kernel<<<1, 64, 0, stream>>>(bsum, boff, NB, row_ptr, N, E);
    scan3_kernel<<<NB, 256, 0, stream>>>(counts, boff, row_ptr, N);
    fill_kernel<<<Gcount, 256, 0, stream>>>(edges, flag, row_ptr, rank,
                                            counts_sh, dis, edata, E, N);

    agg_kernel<<<CDIV(N * 64, 256), 256, 0, stream>>>(A16, row_ptr, edata, dis, b1, B, N);
    gemm_mfma_kernel<<<CDIV(N, 64), 256, 0, stream>>>(B, Wf2h, Wf2l, A16, N);
    agg_kernel<<<CDIV(N * 64, 256), 256, 0, stream>>>(A16, row_ptr, edata, dis, b2, out, N);
}

// Round 6
// 224.922 us; speedup vs baseline: 2.0248x; 1.0206x over previous
//
#include <hip/hip_runtime.h>
#include <hip/hip_bf16.h>

#define CDIV(a,b) (((a)+(b)-1)/(b))

typedef __bf16 bf16x8 __attribute__((ext_vector_type(8)));
typedef float  f32x4  __attribute__((ext_vector_type(4)));

union Frag16 { uint4 u; bf16x8 f; unsigned short s[8]; };
union Pack8  { unsigned short s[4]; uint2 u; };

__device__ __forceinline__ unsigned short f2bf(float f) {   // fp32 -> bf16 RNE
    unsigned u = __float_as_uint(f);
    return (unsigned short)((u + 0x7fff + ((u >> 16) & 1)) >> 16);
}
__device__ __forceinline__ float bf2f(unsigned short s) {
    return __uint_as_float(((unsigned)s) << 16);
}

__device__ __forceinline__ int load_src(const int* e, int f, int E, int i) {
    return f ? e[i] : e[2 * i];
}
__device__ __forceinline__ int load_dst(const int* e, int f, int E, int i) {
    return f ? e[E + i] : e[2 * (E + i)];
}

// ---------------------------------------------------------------------------
// prep: blocks 0,1 swizzle W1/W2 -> hi/lo bf16 MFMA B-fragments; block 2
// zeroes flag then samples edge layout (int64 LE => odd words all zero);
// blocks >=3 zero counts_sh (replaces the hipMemsetAsync dispatch).
// Fragment order: chunk c=(ntile*4+ks)*64+lane, 8 bf16:
//   B[k = ks*32 + (lane>>4)*8 + j][n = ntile*16 + (lane&15)]
// ---------------------------------------------------------------------------
__global__ __launch_bounds__(256) void prep_kernel(const float* __restrict__ W1,
                                                   const float* __restrict__ W2,
                                                   unsigned short* __restrict__ Wf1h,
                                                   unsigned short* __restrict__ Wf1l,
                                                   unsigned short* __restrict__ Wf2h,
                                                   unsigned short* __restrict__ Wf2l,
                                                   const int* __restrict__ edges,
                                                   int* __restrict__ flag, int E,
                                                   int4* __restrict__ zero_base, int Z4) {
    int tid = threadIdx.x;
    if (blockIdx.x == 2) {
        if (tid == 0) *flag = 0;
        __syncthreads();
        int n = min(E, 4096);
        int found = 0;
        for (int j = tid; j < n; j += 256) found |= (edges[2 * j + 1] != 0);
        if (found) *flag = 1;   // benign race within block
        return;
    }
    if (blockIdx.x >= 3) {
        int idx = (blockIdx.x - 3) * 256 + tid;
        if (idx < Z4) zero_base[idx] = make_int4(0, 0, 0, 0);
        return;
    }
    const float* W = (blockIdx.x == 0) ? W1 : W2;
    unsigned short* Wfh = (blockIdx.x == 0) ? Wf1h : Wf2h;
    unsigned short* Wfl = (blockIdx.x == 0) ? Wf1l : Wf2l;
    #pragma unroll
    for (int it = 0; it < 8; ++it) {
        int c = it * 256 + tid;           // chunk in [0, 2048)
        int ntk = c >> 6;
        int lane = c & 63;
        int ks = ntk & 3;
        int ntile = ntk >> 2;
        int quad = lane >> 4, nlo = lane & 15;
        int n = ntile * 16 + nlo;
        Frag16 h, l;
        #pragma unroll
        for (int j = 0; j < 8; ++j) {
            float w = W[(ks * 32 + quad * 8 + j) * 128 + n];
            h.s[j] = f2bf(w);
            float rr = w - bf2f(h.s[j]);
            l.s[j] = f2bf(rr);
        }
        *(uint4*)(Wfh + (size_t)c * 8) = h.u;
        *(uint4*)(Wfl + (size_t)c * 8) = l.u;
    }
}

// ---------------------------------------------------------------------------
// Split-bf16 MFMA GEMM body (fp32 input): out16 = bf16( X @ W ), fp32-accurate
// via xh*wh + xh*wl + xl*wh.  64 rows/block, 4 waves.
// ---------------------------------------------------------------------------
__device__ __forceinline__ void gemm_body(const float* __restrict__ X,
                                          const unsigned short* __restrict__ Wfh,
                                          const unsigned short* __restrict__ Wfl,
                                          unsigned short* __restrict__ out16,
                                          int N, int blk,
                                          unsigned short (*Xh)[136],
                                          unsigned short (*Xl)[136]) {
    int tid = threadIdx.x;
    int row0 = blk * 64;
    #pragma unroll
    for (int it = 0; it < 8; ++it) {
        int f = it * 256 + tid;           // 2048 float4 chunks
        int r = f >> 5, c4 = f & 31;
        float4 v = make_float4(0.f, 0.f, 0.f, 0.f);
        int gr = row0 + r;
        if (gr < N) v = *(const float4*)(X + (size_t)gr * 128 + c4 * 4);
        float vv[4] = {v.x, v.y, v.z, v.w};
        Pack8 h, l;
        #pragma unroll
        for (int j = 0; j < 4; ++j) {
            h.s[j] = f2bf(vv[j]);
            float rr = vv[j] - bf2f(h.s[j]);
            l.s[j] = f2bf(rr);
        }
        *(uint2*)(&Xh[r][c4 * 4]) = h.u;
        *(uint2*)(&Xl[r][c4 * 4]) = l.u;
    }
    __syncthreads();

    int lane = tid & 63;
    int wv = tid >> 6;
    int quad = lane >> 4, nlo = lane & 15;
    f32x4 acc[8];
    #pragma unroll
    for (int t = 0; t < 8; ++t) acc[t] = (f32x4){0.f, 0.f, 0.f, 0.f};

    #pragma unroll
    for (int ks = 0; ks < 4; ++ks) {
        int kcol = ks * 32 + quad * 8;
        Frag16 xh, xl;
        xh.u = *(const uint4*)(&Xh[wv * 16 + nlo][kcol]);
        xl.u = *(const uint4*)(&Xl[wv * 16 + nlo][kcol]);
        #pragma unroll
        for (int t = 0; t < 8; ++t) {
            size_t cidx = ((size_t)(t * 4 + ks) * 64 + lane) * 8;
            Frag16 wh, wl;
            wh.u = *(const uint4*)(Wfh + cidx);
            wl.u = *(const uint4*)(Wfl + cidx);
            acc[t] = __builtin_amdgcn_mfma_f32_16x16x32_bf16(xh.f, wh.f, acc[t], 0, 0, 0);
            acc[t] = __builtin_amdgcn_mfma_f32_16x16x32_bf16(xh.f, wl.f, acc[t], 0, 0, 0);
            acc[t] = __builtin_amdgcn_mfma_f32_16x16x32_bf16(xl.f, wh.f, acc[t], 0, 0, 0);
        }
    }
    // C/D layout: col = lane&15, row = quad*4 + reg
    #pragma unroll
    for (int rg = 0; rg < 4; ++rg) {
        int gr = row0 + wv * 16 + quad * 4 + rg;
        if (gr < N) {
            #pragma unroll
            for (int t = 0; t < 8; ++t)
                out16[(size_t)gr * 128 + t * 16 + nlo] = f2bf(acc[t][rg]);
        }
    }
}

// ---------------------------------------------------------------------------
// FAT kernel: blocks [0,Ggemm) do layer-1 GEMM (x@W1 -> A16); the rest do the
// sharded degree count (atomics). Independent inputs; pipes overlap per CU.
// ---------------------------------------------------------------------------
__global__ __launch_bounds__(256) void fat_kernel(const float* __restrict__ X,
                                                  const unsigned short* __restrict__ Wfh,
                                                  const unsigned short* __restrict__ Wfl,
                                                  unsigned short* __restrict__ out16,
                                                  int N, int Ggemm,
                                                  const int* __restrict__ edges,
                                                  const int* __restrict__ flag,
                                                  int* __restrict__ counts_sh,
                                                  int* __restrict__ rank, int E) {
    __shared__ unsigned short Xh[64][136];   // +8 pad: 2-way conflicts only
    __shared__ unsigned short Xl[64][136];
    if (blockIdx.x < (unsigned)Ggemm) {
        gemm_body(X, Wfh, Wfl, out16, N, blockIdx.x, Xh, Xl);
        return;
    }
    int e = (blockIdx.x - Ggemm) * 256 + threadIdx.x;
    if (e >= E) return;
    int f = *flag;
    int d = load_dst(edges, f, E, e);
    int s = blockIdx.x & 7;
    int r = atomicAdd(&counts_sh[s * N + d], 1);
    rank[e] = (r << 3) | s;
}

// ---------------------------------------------------------------------------
// Layer-2 GEMM, bf16 input: A-fragments loaded DIRECTLY from global (row-major
// bf16 == A-frag layout: lane l holds A[m=l&15][k=(l>>4)*8+j]).  No LDS.
// W2 stays hi/lo split (2 MFMAs/tile) for accuracy.  out16 = bf16(h1 @ W2).
// ---------------------------------------------------------------------------
__global__ __launch_bounds__(256) void gemm_h1_kernel(const unsigned short* __restrict__ H1,
                                                      const unsigned short* __restrict__ Wfh,
                                                      const unsigned short* __restrict__ Wfl,
                                                      unsigned short* __restrict__ out16,
                                                      int N) {
    int tid = threadIdx.x;
    int lane = tid & 63, wv = tid >> 6;
    int quad = lane >> 4, nlo = lane & 15;
    int row0 = blockIdx.x * 64 + wv * 16;
    int arow = min(row0 + nlo, N - 1);        // clamp; OOB rows never stored
    Frag16 xa[4];
    #pragma unroll
    for (int ks = 0; ks < 4; ++ks)
        xa[ks].u = *(const uint4*)(H1 + (size_t)arow * 128 + ks * 32 + quad * 8);

    f32x4 acc[8];
    #pragma unroll
    for (int t = 0; t < 8; ++t) acc[t] = (f32x4){0.f, 0.f, 0.f, 0.f};

    #pragma unroll
    for (int ks = 0; ks < 4; ++ks) {
        #pragma unroll
        for (int t = 0; t < 8; ++t) {
            size_t cidx = ((size_t)(t * 4 + ks) * 64 + lane) * 8;
            Frag16 wh, wl;
            wh.u = *(const uint4*)(Wfh + cidx);
            wl.u = *(const uint4*)(Wfl + cidx);
            acc[t] = __builtin_amdgcn_mfma_f32_16x16x32_bf16(xa[ks].f, wh.f, acc[t], 0, 0, 0);
            acc[t] = __builtin_amdgcn_mfma_f32_16x16x32_bf16(xa[ks].f, wl.f, acc[t], 0, 0, 0);
        }
    }
    #pragma unroll
    for (int rg = 0; rg < 4; ++rg) {
        int gr = row0 + quad * 4 + rg;
        if (gr < N) {
            #pragma unroll
            for (int t = 0; t < 8; ++t)
                out16[(size_t)gr * 128 + t * 16 + nlo] = f2bf(acc[t][rg]);
        }
    }
}

// ---------------------------------------------------------------------------
// merge_dis: shard counts -> shard base offsets (in place), degree -> counts,
// dis = rsqrt(deg+1); per-1024-node sums -> bsum.
// ---------------------------------------------------------------------------
__global__ __launch_bounds__(256) void merge_dis_kernel(int* __restrict__ counts_sh,
                                                        int* __restrict__ counts,
                                                        float* __restrict__ dis,
                                                        int* __restrict__ bsum, int N) {
    __shared__ int red[4];
    int tid = threadIdx.x;
    int bs = 0;
    #pragma unroll
    for (int j = 0; j < 4; ++j) {
        int d = blockIdx.x * 1024 + j * 256 + tid;
        if (d < N) {
            int run = 0;
            #pragma unroll
            for (int s = 0; s < 8; ++s) {
                int v = counts_sh[s * N + d];
                counts_sh[s * N + d] = run;
                run += v;
            }
            counts[d] = run;
            dis[d] = rsqrtf((float)(run + 1));
            bs += run;
        }
    }
    #pragma unroll
    for (int off = 32; off >= 1; off >>= 1) bs += __shfl_down(bs, off, 64);
    if ((tid & 63) == 0) red[tid >> 6] = bs;
    __syncthreads();
    if (tid == 0) bsum[blockIdx.x] = red[0] + red[1] + red[2] + red[3];
}

__global__ void scan2_kernel(const int* __restrict__ bsum, int* __restrict__ boff,
                             int B, int* __restrict__ row_ptr, int N, int E) {
    int lane = threadIdx.x;
    int carry = 0;
    for (int base = 0; base < B; base += 64) {
        int i = base + lane;
        int v = (i < B) ? bsum[i] : 0;
        int x = v;
        #pragma unroll
        for (int off = 1; off < 64; off <<= 1) {
            int t = __shfl_up(x, off, 64);
            if (lane >= off) x += t;
        }
        if (i < B) boff[i] = carry + x - v;
        carry += __shfl(x, 63, 64);
    }
    if (lane == 0) row_ptr[N] = E;
}

__global__ __launch_bounds__(256) void scan3_kernel(const int* __restrict__ counts,
                                                    const int* __restrict__ boff,
                                                    int* __restrict__ row_ptr, int N) {
    __shared__ int wsum[4];
    int tid = threadIdx.x;
    int lane = tid & 63, wv = tid >> 6;
    int base = blockIdx.x * 1024 + tid * 4;
    int c[4];
    #pragma unroll
    for (int j = 0; j < 4; ++j) c[j] = (base + j < N) ? counts[base + j] : 0;
    int tsum = c[0] + c[1] + c[2] + c[3];
    int x = tsum;
    #pragma unroll
    for (int off = 1; off < 64; off <<= 1) {
        int t = __shfl_up(x, off, 64);
        if (lane >= off) x += t;
    }
    int texcl = x - tsum;
    if (lane == 63) wsum[wv] = x;
    __syncthreads();
    int woff = 0;
    for (int w = 0; w < wv; ++w) woff += wsum[w];
    int off0 = boff[blockIdx.x] + woff + texcl;
    int run = 0;
    #pragma unroll
    for (int j = 0; j < 4; ++j) {
        if (base + j < N) row_ptr[base + j] = off0 + run;
        run += c[j];
    }
}

// CSR fill (atomic-free): pos = row_ptr[d] + shard_base + local_rank.
__global__ void fill_kernel(const int* __restrict__ edges, const int* __restrict__ flag,
                            const int* __restrict__ row_ptr, const int* __restrict__ rank,
                            const int* __restrict__ counts_sh,
                            const float* __restrict__ dis, int2* __restrict__ edata,
                            int E, int N) {
    int e = blockIdx.x * blockDim.x + threadIdx.x;
    if (e >= E) return;
    int f = *flag;
    int s = load_src(edges, f, E, e);
    int d = load_dst(edges, f, E, e);
    int rk = rank[e];
    int sh = rk & 7;
    int pos = row_ptr[d] + counts_sh[sh * N + d] + (rk >> 3);
    edata[pos] = make_int2(s, __float_as_int(dis[s]));
}

// ---------------------------------------------------------------------------
// Aggregation: one wave per node, bf16x2 (4B)/lane gathers, fp32 accumulate,
// bias+relu epilogue.  BF16OUT: write bf16 (inter-layer) or fp32 (final out).
// Edge loop unrolled x8 with masked batches (invalid slots alias edata[e]).
// ---------------------------------------------------------------------------
template <bool BF16OUT>
__global__ __launch_bounds__(256) void agg_kernel(const unsigned short* __restrict__ H16,
                                                  const int* __restrict__ row_ptr,
                                                  const int2* __restrict__ edata,
                                                  const float* __restrict__ dis,
                                                  const float* __restrict__ bias,
                                                  void* __restrict__ outp, int N) {
    int wid = (blockIdx.x * blockDim.x + threadIdx.x) >> 6;
    int lane = threadIdx.x & 63;
    if (wid >= N) return;
    const ushort2* H2 = (const ushort2*)H16;
    float dd = dis[wid];
    ushort2 hv = H2[(size_t)wid * 64 + lane];
    float wself = dd * dd;
    float2 acc = make_float2(bf2f(hv.x) * wself, bf2f(hv.y) * wself);
    int e0 = __builtin_amdgcn_readfirstlane(row_ptr[wid]);
    int e1 = __builtin_amdgcn_readfirstlane(row_ptr[wid + 1]);
    for (int e = e0; e < e1; e += 8) {
        int rem = e1 - e;
        int   sj[8];
        float wj[8];
        #pragma unroll
        for (int j = 0; j < 8; ++j) {
            bool valid = j < rem;
            int2 ed = edata[valid ? e + j : e];
            sj[j] = ed.x;
            wj[j] = valid ? __int_as_float(ed.y) * dd : 0.f;
        }
        ushort2 aj[8];
        #pragma unroll
        for (int j = 0; j < 8; ++j)
            aj[j] = H2[(size_t)sj[j] * 64 + lane];
        #pragma unroll
        for (int j = 0; j < 8; ++j) {
            acc.x += bf2f(aj[j].x) * wj[j];
            acc.y += bf2f(aj[j].y) * wj[j];
        }
    }
    float2 b = ((const float2*)bias)[lane];
    float ox = fmaxf(acc.x + b.x, 0.f);
    float oy = fmaxf(acc.y + b.y, 0.f);
    if (BF16OUT) {
        ushort2 o = make_ushort2(f2bf(ox), f2bf(oy));
        ((ushort2*)outp)[(size_t)wid * 64 + lane] = o;
    } else {
        ((float2*)outp)[(size_t)wid * 64 + lane] = make_float2(ox, oy);
    }
}

extern "C" void kernel_launch(void* const* d_in, const int* in_sizes, int n_in,
                              void* d_out, int out_size, void* d_ws, size_t ws_size,
                              hipStream_t stream) {
    const float* x    = (const float*)d_in[0];
    const int*  edges = (const int*)d_in[1];
    const float* W1   = (const float*)d_in[2];
    const float* b1   = (const float*)d_in[3];
    const float* W2   = (const float*)d_in[4];
    const float* b2   = (const float*)d_in[5];
    float* out = (float*)d_out;

    const int F = 128;
    const int N = in_sizes[0] / F;
    const int E = in_sizes[1] / 2;
    const int NB = CDIV(N, 1024);          // scan blocks (<=64)
    const int Ggemm = CDIV(N, 64);
    const int Gcount = CDIV(E, 256);

    #define AL4(v) (((v) + 3) & ~3)        // keep segments 16B-aligned
    unsigned short* A16 = (unsigned short*)d_ws;            // N*128 bf16 (gemm1 out; reused for h1@W2)
    unsigned short* H1  = A16 + (size_t)AL4(N * F);         // N*128 bf16 (agg1 out)
    float* dis      = (float*)(H1 + (size_t)AL4(N * F));    // N
    int*  counts    = (int*)(dis + AL4(N));                 // N
    int*  counts_sh = counts + AL4(N);                      // 8N  } zeroed by prep
    int*  flag      = counts_sh + AL4(8 * N);               // 4   } zeroed by prep blk2
    int*  row_ptr   = flag + 4;                             // N+4
    int*  bsum      = row_ptr + AL4(N + 1);                 // 64
    int*  boff      = bsum + 64;                            // 64
    int*  rank      = boff + 64;                            // E
    int2* edata     = (int2*)(rank + AL4(E));               // E
    unsigned short* Wf1h = (unsigned short*)(edata + E);    // 16384 each
    unsigned short* Wf1l = Wf1h + 16384;
    unsigned short* Wf2h = Wf1l + 16384;
    unsigned short* Wf2l = Wf2h + 16384;

    const int Z4 = AL4(8 * N) / 4;         // int4s of counts_sh to zero
    const int Gprep = 3 + CDIV(Z4, 256);

    prep_kernel<<<Gprep, 256, 0, stream>>>(W1, W2, Wf1h, Wf1l, Wf2h, Wf2l,
                                           edges, flag, E, (int4*)counts_sh, Z4);
    fat_kernel<<<Ggemm + Gcount, 256, 0, stream>>>(x, Wf1h, Wf1l, A16, N, Ggemm,
                                                   edges, flag, counts_sh, rank, E);
    merge_dis_kernel<<<NB, 256, 0, stream>>>(counts_sh, counts, dis, bsum, N);
    scan2_kernel<<<1, 64, 0, stream>>>(bsum, boff, NB, row_ptr, N, E);
    scan3_kernel<<<NB, 256, 0, stream>>>(counts, boff, row_ptr, N);
    fill_kernel<<<Gcount, 256, 0, stream>>>(edges, flag, row_ptr, rank,
                                            counts_sh, dis, edata, E, N);

    agg_kernel<true><<<CDIV(N * 64, 256), 256, 0, stream>>>(A16, row_ptr, edata, dis, b1, H1, N);
    gemm_h1_kernel<<<CDIV(N, 64), 256, 0, stream>>>(H1, Wf2h, Wf2l, A16, N);
    agg_kernel<false><<<CDIV(N * 64, 256), 256, 0, stream>>>(A16, row_ptr, edata, dis, b2, out, N);
}